// Round 4
// baseline (47.191 us; speedup 1.0000x reference)
//
#include <hip/hip_runtime.h>

// MakeCutouts: 32 random crops (size in [224,512]) of a [2,3,512,512] fp32
// image, each adaptive-avg-pooled (PyTorch semantics) to 224x224.
// Output: [32*2, 3, 224, 224] fp32.
//
// R3: bins span up to 4x4 (NOT 3x3 — R2's bug: ceil(frac+2.2857) can be 4).
// Use row prefix sums: P[pl][y][x] = sum of input[pl][y][0..x-1], stored in
// d_ws (6x512x513 fp32 = 6.3 MB, fully rewritten each call). Each output bin
// is then sum over <=4 predicated row taps of P[y][xe]-P[y][xs]: 48
// independent loads/thread (vs 96 for a 4x4 tap stencil), exact for any
// x-span, one vmcnt wait.

constexpr int CUT    = 224;
constexpr int BC     = 6;          // B*C = 2*3
constexpr int HH     = 512;
constexpr int WW     = 512;
constexpr int PIX    = CUT * CUT;  // 50176 = 196 * 256
constexpr int PW     = WW + 1;     // 513 columns in prefix rows
constexpr int PPLANE = HH * PW;

// One wave per row: lane-local inclusive prefix of 8 elements, then a
// __shfl_up wave scan of lane totals. dst[x] = sum src[0..x-1], dst[0]=0.
__global__ __launch_bounds__(256) void row_prefix_kernel(
    const float* __restrict__ in,   // [6*512, 512]
    float*       __restrict__ P)    // [6*512, 513]
{
    const int wid  = threadIdx.x >> 6;           // wave in block (4 rows/block)
    const int lane = threadIdx.x & 63;
    const int row  = blockIdx.x * 4 + wid;       // 0..3071 = plane*512 + y

    const float* __restrict__ src = in + (size_t)row * WW;
    float*       __restrict__ dst = P  + (size_t)row * PW;

    const float4 a = *(const float4*)(src + lane * 8);
    const float4 b = *(const float4*)(src + lane * 8 + 4);
    const float v[8] = {a.x, a.y, a.z, a.w, b.x, b.y, b.z, b.w};

    float pref[8];
    float run = 0.f;
    #pragma unroll
    for (int k = 0; k < 8; ++k) { run += v[k]; pref[k] = run; }

    float scan = run;                            // inclusive scan of lane totals
    #pragma unroll
    for (int d = 1; d < 64; d <<= 1) {
        const float o = __shfl_up(scan, d, 64);
        if (lane >= d) scan += o;
    }
    const float excl = scan - run;               // exclusive prefix for this lane

    if (lane == 0) dst[0] = 0.f;
    #pragma unroll
    for (int k = 0; k < 8; ++k) dst[lane * 8 + 1 + k] = excl + pref[k];
}

__global__ __launch_bounds__(256) void cutout_kernel(
    const float* __restrict__ P,      // [6, 512, 513] row prefix sums
    const int*   __restrict__ sizes,  // [32]
    const int*   __restrict__ offx,   // [32]
    const int*   __restrict__ offy,   // [32]
    float*       __restrict__ out)    // [32, 6, 224, 224] flat
{
    const int p = blockIdx.x * 256 + threadIdx.x;  // pixel in 224x224
    const int n = blockIdx.y;                      // cutout index (uniform)

    const int i = p / CUT;
    const int j = p - i * CUT;

    const int sz = sizes[n];   // uniform -> scalar
    const int oy = offy[n];
    const int ox = offx[n];

    const int sy = (i * sz) / CUT;
    const int dy = ((i + 1) * sz + CUT - 1) / CUT - sy;   // 1..4
    const int sx = (j * sz) / CUT;
    const int dx = ((j + 1) * sz + CUT - 1) / CUT - sx;   // 1..4

    const int ys = oy + sy;            // absolute first row; ys+dy-1 <= 511
    const int xs = ox + sx;            // absolute col window [xs, xe), xe <= 512
    const int xe = xs + dx;

    // 4 predicated row taps; masked taps re-read the last valid row, weight 0.
    const int q0 = ys * PW;
    const int q1 = q0 + (dy > 1 ? PW : 0);
    const int q2 = q1 + (dy > 2 ? PW : 0);
    const int q3 = q2 + (dy > 3 ? PW : 0);
    const float w1 = dy > 1 ? 1.f : 0.f;
    const float w2 = dy > 2 ? 1.f : 0.f;
    const float w3 = dy > 3 ? 1.f : 0.f;

    float acc[BC];
    #pragma unroll
    for (int pl = 0; pl < BC; ++pl) {
        const float* __restrict__ pb = P + pl * PPLANE;
        float s =      (pb[q0 + xe] - pb[q0 + xs]);
        s += w1 * (pb[q1 + xe] - pb[q1 + xs]);
        s += w2 * (pb[q2 + xe] - pb[q2 + xs]);
        s += w3 * (pb[q3 + xe] - pb[q3 + xs]);
        acc[pl] = s;
    }

    const float r = __builtin_amdgcn_rcpf((float)(dy * dx));
    float* o = out + (size_t)n * BC * PIX + p;
    #pragma unroll
    for (int pl = 0; pl < BC; ++pl)
        __builtin_nontemporal_store(acc[pl] * r, o + pl * PIX);
}

extern "C" void kernel_launch(void* const* d_in, const int* in_sizes, int n_in,
                              void* d_out, int out_size, void* d_ws, size_t ws_size,
                              hipStream_t stream) {
    const float* in    = (const float*)d_in[0];
    const int*   sizes = (const int*)d_in[1];
    const int*   offx  = (const int*)d_in[2];
    const int*   offy  = (const int*)d_in[3];
    float*       out   = (float*)d_out;
    float*       P     = (float*)d_ws;   // 6*512*513*4 B = 6.3 MB

    row_prefix_kernel<<<dim3(BC * HH / 4), dim3(256), 0, stream>>>(in, P);
    cutout_kernel<<<dim3(PIX / 256, 32), dim3(256), 0, stream>>>(P, sizes, offx, offy, out);
}

// Round 5
// 20.898 us; speedup vs baseline: 2.2581x; 2.2581x over previous
//
#include <hip/hip_runtime.h>

// MakeCutouts: 32 random crops (size sz in [224,512]) of a [2,3,512,512] fp32
// image, each adaptive-avg-pooled (PyTorch semantics) to 224x224.
// Output: [32*2, 3, 224, 224] fp32.
//
// R4: block = (output row i, cutout n) -> sy,dy are block-UNIFORM (scalar).
// Phase 1: threads load the dy (<=4) input rows of the crop's column span
// with stride-1 coalesced loads (lane t <-> col ox+t), accumulating the
// vertical sum in registers; write once to LDS packed as float2 plane-pairs.
// Phase 2: thread j<224 takes <=4 predicated horizontal taps (exact for
// dx in 1..4) per plane-pair from LDS, scales by 1/(dy*dx), stores coalesced
// nontemporal. Kills the scattered-gather TA cost that bounded R1/R3
// (lanes ~2.3 elements apart -> ~10 cachelines per wave-load).

constexpr int CUT   = 224;
constexpr int BC    = 6;          // B*C = 2*3
constexpr int HH    = 512;
constexpr int WW    = 512;
constexpr int PIX   = CUT * CUT;  // 50176
constexpr int PLANE = HH * WW;

__global__ __launch_bounds__(256) void cutout_kernel(
    const float* __restrict__ in,     // [6, 512, 512] planes
    const int*   __restrict__ sizes,  // [32]
    const int*   __restrict__ offx,   // [32]
    const int*   __restrict__ offy,   // [32]
    float*       __restrict__ out)    // [32, 6, 224, 224] flat
{
    __shared__ float2 vsum[3][WW];    // [plane-pair][col rel. ox] = 12 KB

    const int i = blockIdx.x;         // output row (uniform)
    const int n = blockIdx.y;         // cutout (uniform)
    const int t = threadIdx.x;

    const int sz = sizes[n];          // scalar loads
    const int oy = offy[n];
    const int ox = offx[n];

    const int sy = (i * sz) / CUT;                        // uniform
    const int dy = ((i + 1) * sz + CUT - 1) / CUT - sy;   // 1..4, uniform

    const float* __restrict__ base = in + (oy + sy) * WW + ox;

    // Phase 1: vertical sums over dy rows, cols t and t+256 (crop-relative).
    float a0=0.f,a1=0.f,a2=0.f,a3=0.f,a4=0.f,a5=0.f;  // col t
    float b0=0.f,b1=0.f,b2=0.f,b3=0.f,b4=0.f,b5=0.f;  // col t+256
    const bool c0 = t < sz;           // sz >= 224; only lanes 224..255 can fail
    const bool c1 = t + 256 < sz;

    for (int r = 0; r < dy; ++r) {    // uniform trip count
        const float* __restrict__ rp = base + r * WW;
        if (c0) {
            a0 += rp[0*PLANE + t]; a1 += rp[1*PLANE + t]; a2 += rp[2*PLANE + t];
            a3 += rp[3*PLANE + t]; a4 += rp[4*PLANE + t]; a5 += rp[5*PLANE + t];
        }
        if (c1) {
            const int u = t + 256;
            b0 += rp[0*PLANE + u]; b1 += rp[1*PLANE + u]; b2 += rp[2*PLANE + u];
            b3 += rp[3*PLANE + u]; b4 += rp[4*PLANE + u]; b5 += rp[5*PLANE + u];
        }
    }
    if (c0) {
        vsum[0][t] = make_float2(a0, a1);
        vsum[1][t] = make_float2(a2, a3);
        vsum[2][t] = make_float2(a4, a5);
    }
    if (c1) {
        const int u = t + 256;
        vsum[0][u] = make_float2(b0, b1);
        vsum[1][u] = make_float2(b2, b3);
        vsum[2][u] = make_float2(b4, b5);
    }
    __syncthreads();

    // Phase 2: horizontal pooling from LDS, 4 predicated taps (dx in 1..4).
    if (t < CUT) {
        const int sx = (t * sz) / CUT;                        // crop-relative
        const int dx = ((t + 1) * sz + CUT - 1) / CUT - sx;   // 1..4
        const int x1 = sx + (dx > 1 ? 1 : 0);                 // clamped taps
        const int x2 = x1 + (dx > 2 ? 1 : 0);
        const int x3 = x2 + (dx > 3 ? 1 : 0);
        const float w1 = dx > 1 ? 1.f : 0.f;
        const float w2 = dx > 2 ? 1.f : 0.f;
        const float w3 = dx > 3 ? 1.f : 0.f;
        const float rr = __builtin_amdgcn_rcpf((float)(dy * dx));

        float* o = out + (size_t)n * BC * PIX + i * CUT + t;
        #pragma unroll
        for (int pr = 0; pr < 3; ++pr) {
            const float2 v0 = vsum[pr][sx];
            const float2 v1 = vsum[pr][x1];
            const float2 v2 = vsum[pr][x2];
            const float2 v3 = vsum[pr][x3];
            const float se = v0.x + w1 * v1.x + w2 * v2.x + w3 * v3.x;
            const float so = v0.y + w1 * v1.y + w2 * v2.y + w3 * v3.y;
            __builtin_nontemporal_store(se * rr, o + (2 * pr    ) * PIX);
            __builtin_nontemporal_store(so * rr, o + (2 * pr + 1) * PIX);
        }
    }
}

extern "C" void kernel_launch(void* const* d_in, const int* in_sizes, int n_in,
                              void* d_out, int out_size, void* d_ws, size_t ws_size,
                              hipStream_t stream) {
    const float* in    = (const float*)d_in[0];
    const int*   sizes = (const int*)d_in[1];
    const int*   offx  = (const int*)d_in[2];
    const int*   offy  = (const int*)d_in[3];
    float*       out   = (float*)d_out;

    cutout_kernel<<<dim3(CUT, 32), dim3(256), 0, stream>>>(in, sizes, offx, offy, out);
}